// Round 8
// baseline (342.039 us; speedup 1.0000x reference)
//
#include <hip/hip_runtime.h>
#include <math.h>

#define Bn 8
#define NCn 384
#define Hn 32
#define Wn 32
#define Gn 6
#define GCn 64
#define HEADSn 12
#define Dn 32
#define HKn 15
#define WKn 15
#define NSn 225
#define NQn 1024
#define NKVn 900
#define VSTRIDE 960   // V row stride in bf16; covers max frag read (offset 960);
                      // keys 900..959 zero-filled (stale-bits NaN guard, R3 bug).

typedef __attribute__((ext_vector_type(8))) short short8;
typedef __attribute__((ext_vector_type(4))) float floatx4;

__device__ __forceinline__ float gelu_f(float x) {
    return 0.5f * x * (1.0f + erff(x * 0.70710678118654752f));
}

__device__ __forceinline__ ushort f2bf(float x) {
    unsigned u = __float_as_uint(x);
    u = (u + 0x7FFF + ((u >> 16) & 1)) >> 16;   // RNE
    return (ushort)u;
}

// cheap round-half-up bf16 pack (hot P path; <= 1 ulp vs RNE)
__device__ __forceinline__ ushort f2bf_fast(float x) {
    return (ushort)((__float_as_uint(x) + 0x8000u) >> 16);
}

// ---------------------------------------------------------------------------
// k_prep: fused preprocessing, one launch, 1024 blocks.
//  id [0,768):    transpose4 -> dataT (48,1024,256) bf16   (bg=id%48, hwt=id/48)
//  id [768,896):  transposeQ -> qXT  (8,1024,384) bf16     (b=j&7, hwt=j>>3)
//  id [896,1024): cvtw grid-stride -> wb (606208 bf16)
// ---------------------------------------------------------------------------
__global__ __launch_bounds__(256) void k_prep(
    const float* __restrict__ xr1, const float* __restrict__ xr2,
    const float* __restrict__ xx1, const float* __restrict__ xx2,
    const float* __restrict__ query,
    const float* __restrict__ w1, const float* __restrict__ qw,
    const float* __restrict__ kw, const float* __restrict__ vw,
    const float* __restrict__ ow,
    ushort* __restrict__ dataT, ushort* __restrict__ qXT,
    ushort* __restrict__ wb)
{
    __shared__ float lds[64 * 65];
    const int id = blockIdx.x;
    const int tid = threadIdx.x;

    if (id < 768) {
        const int bg = id % 48, hwt = id / 48;
        const int b = bg / Gn, g = bg % Gn;
        for (int kc = 0; kc < 4; ++kc) {
            for (int idx = tid; idx < 4096; idx += 256) {
                int cl = idx >> 6, hwl = idx & 63;
                int gch = g * 256 + kc * 64 + cl;
                int m = gch / NCn, cm = gch % NCn;
                const float* img = (m == 0) ? xr1 : (m == 1) ? xr2 : (m == 2) ? xx1 : xx2;
                lds[cl * 65 + hwl] = img[(b * NCn + cm) * NQn + hwt * 64 + hwl];
            }
            __syncthreads();
            for (int idx = tid; idx < 4096; idx += 256) {
                int hwl = idx >> 6, cl = idx & 63;
                dataT[((size_t)bg * NQn + hwt * 64 + hwl) * 256 + kc * 64 + cl] =
                    f2bf(lds[cl * 65 + hwl]);
            }
            __syncthreads();
        }
    } else if (id < 896) {
        const int j = id - 768;
        const int b = j & 7, hwt = j >> 3;
        for (int kc = 0; kc < 6; ++kc) {
            for (int idx = tid; idx < 4096; idx += 256) {
                int cl = idx >> 6, hwl = idx & 63;
                lds[cl * 65 + hwl] =
                    query[((size_t)b * NCn + kc * 64 + cl) * NQn + hwt * 64 + hwl];
            }
            __syncthreads();
            for (int idx = tid; idx < 4096; idx += 256) {
                int hwl = idx >> 6, cl = idx & 63;
                qXT[((size_t)b * NQn + hwt * 64 + hwl) * NCn + kc * 64 + cl] =
                    f2bf(lds[cl * 65 + hwl]);
            }
            __syncthreads();
        }
    } else {
        const int j = id - 896;   // 0..127
        for (int i = j * 256 + tid; i < 606208; i += 128 * 256) {
            float v;
            if      (i < 16384)  v = w1[i];
            else if (i < 163840) v = qw[i - 16384];
            else if (i < 311296) v = kw[i - 163840];
            else if (i < 458752) v = vw[i - 311296];
            else                 v = ow[i - 458752];
            wb[i] = f2bf(v);
        }
    }
}

// ---------------------------------------------------------------------------
// k_offsample: fused depthwise-offsets + bilinear sampling.
// Grid (48, 4): x = bg, y = map. Phase 1 computes all 225 positions for this
// bg into LDS (redundant across the 4 map-blocks — trivial math); phase 2
// does this map's gathers. t1T is (bg, hw, c) fp32 so phase-1 depthwise reads
// are lane-coalesced (4 lines/read vs 64 in the old (bg,c,hw) layout).
// ---------------------------------------------------------------------------
__global__ __launch_bounds__(256) void k_offsample(
    const float* __restrict__ t1T, const float* __restrict__ w2,
    const float* __restrict__ b2, const float* __restrict__ w3,
    const float* __restrict__ xr1, const float* __restrict__ xr2,
    const float* __restrict__ xx1, const float* __restrict__ xx2,
    ushort* __restrict__ smpT)
{
    __shared__ float pos[NSn * 2];
    const int bg = blockIdx.x;
    const int m  = blockIdx.y;
    const int b = bg / Gn, g = bg % Gn;
    const int tid = threadIdx.x;
    const int w = tid >> 6, lane = tid & 63;

    // phase 1: positions (lane = channel)
    const float* tbase = t1T + ((size_t)bg << 10) * 64;
    const float* wp = w2 + lane * 9;
    const float bias2 = b2[lane];
    const float w3y = w3[lane], w3x = w3[64 + lane];
    for (int s = w; s < NSn; s += 4) {
        const int hk = s / WKn, wk = s % WKn;
        float sv = bias2;
        #pragma unroll
        for (int i = 0; i < 3; ++i)
            #pragma unroll
            for (int jx = 0; jx < 3; ++jx)
                sv += tbase[((hk * 2 + i) * Wn + wk * 2 + jx) * 64 + lane] * wp[i * 3 + jx];
        float gv = gelu_f(sv);
        float ay = w3y * gv;
        float ax = w3x * gv;
        #pragma unroll
        for (int off = 32; off > 0; off >>= 1) {
            ay += __shfl_xor(ay, off, 64);
            ax += __shfl_xor(ax, off, 64);
        }
        if (lane == 0) {
            float fy = tanhf(ay) * (2.0f / 14.0f);
            float fx = tanhf(ax) * (2.0f / 14.0f);
            float cy = (float)(hk * 2 + 1) * (2.0f / 31.0f) - 1.0f;
            float cx = (float)(wk * 2 + 1) * (2.0f / 31.0f) - 1.0f;
            float py = fminf(fmaxf(fy + cy, -1.0f), 1.0f);
            float px = fminf(fmaxf(fx + cx, -1.0f), 1.0f);
            pos[s * 2 + 0] = (py + 1.0f) * 0.5f * 31.0f;
            pos[s * 2 + 1] = (px + 1.0f) * 0.5f * 31.0f;
        }
    }
    __syncthreads();

    // phase 2: gathers for map m
    const float* img = (m == 0) ? xr1 : (m == 1) ? xr2 : (m == 2) ? xx1 : xx2;
    for (int idx = tid; idx < 64 * NSn; idx += 256) {
        int c = idx & 63, s = idx >> 6;
        float py = pos[s * 2 + 0];
        float px = pos[s * 2 + 1];
        float y0f = floorf(py), x0f = floorf(px);
        float wy = py - y0f, wx = px - x0f;
        int y0 = (int)y0f, x0 = (int)x0f;
        int y1 = min(y0 + 1, Hn - 1), x1 = min(x0 + 1, Wn - 1);
        const float* base = img + (b * NCn + g * GCn + c) * NQn;
        float v00 = base[y0 * Wn + x0], v01 = base[y0 * Wn + x1];
        float v10 = base[y1 * Wn + x0], v11 = base[y1 * Wn + x1];
        float v = v00 * (1.0f - wy) * (1.0f - wx) + v01 * (1.0f - wy) * wx
                + v10 * wy * (1.0f - wx) + v11 * wy * wx;
        smpT[((size_t)b * NQn + m * NSn + s) * NCn + g * GCn + c] = f2bf(v);
    }
}

// ---------------------------------------------------------------------------
// MFMA GEMM (R5-measured form: simple in-loop loads, compiler-scheduled).
// C[b,m,n] = sum_k A[m,k] * XT[b,n,k]; grid (nb, mb, b); wave tile 32m x 64n.
// mode 0: fp32 (b,384,N) + resid
// mode 3: GELU -> t1T (bg, hw, c) fp32, float4 over the m-contiguous r regs
// ---------------------------------------------------------------------------
__global__ __launch_bounds__(256) void k_gemm(
    const ushort* __restrict__ A, const ushort* __restrict__ XT,
    const float* __restrict__ bias, const float* __restrict__ resid,
    float* __restrict__ Yf,
    int K, int Npad, int N, int mode)
{
    const int nb = blockIdx.x, mb = blockIdx.y, b = blockIdx.z;
    const int w = threadIdx.x >> 6, lane = threadIdx.x & 63;
    const int l16 = lane & 15, quad = lane >> 4;
    const int m0 = mb * 32;
    const int n0 = nb * 256 + w * 64;

    floatx4 zero = {0.0f, 0.0f, 0.0f, 0.0f};
    floatx4 acc[2][4] = {{zero, zero, zero, zero}, {zero, zero, zero, zero}};

    const ushort* a0 = A + (size_t)(m0 + l16) * K + quad * 8;
    const ushort* a1 = a0 + (size_t)16 * K;
    const ushort* bp = XT + ((size_t)b * Npad + n0 + l16) * K + quad * 8;

    #pragma unroll 2
    for (int k0 = 0; k0 < K; k0 += 32) {
        short8 af0 = *(const short8*)(a0 + k0);
        short8 af1 = *(const short8*)(a1 + k0);
        short8 bf[4];
        #pragma unroll
        for (int t = 0; t < 4; ++t)
            bf[t] = *(const short8*)(bp + (size_t)(t * 16) * K + k0);
        #pragma unroll
        for (int t = 0; t < 4; ++t) {
            acc[0][t] = __builtin_amdgcn_mfma_f32_16x16x32_bf16(af0, bf[t], acc[0][t], 0, 0, 0);
            acc[1][t] = __builtin_amdgcn_mfma_f32_16x16x32_bf16(af1, bf[t], acc[1][t], 0, 0, 0);
        }
    }

    if (mode == 0) {
        #pragma unroll
        for (int a = 0; a < 2; ++a)
            #pragma unroll
            for (int r = 0; r < 4; ++r) {
                int m = m0 + a * 16 + quad * 4 + r;
                float bb = bias[m];
                #pragma unroll
                for (int t = 0; t < 4; ++t) {
                    int n = n0 + t * 16 + l16;
                    size_t o = ((size_t)b * NCn + m) * N + n;
                    Yf[o] = acc[a][t][r] + bb + resid[o];
                }
            }
    } else {  // mode 3: GELU -> t1T (bg, hw, c): float4 over r (m-contiguous)
        #pragma unroll
        for (int a = 0; a < 2; ++a) {
            const int mbase = m0 + a * 16 + quad * 4;     // 4-aligned
            float bb[4];
            #pragma unroll
            for (int r = 0; r < 4; ++r) bb[r] = bias[mbase + r];
            #pragma unroll
            for (int t = 0; t < 4; ++t) {
                int n = n0 + t * 16 + l16;
                float4 v;
                v.x = gelu_f(acc[a][t][0] + bb[0]);
                v.y = gelu_f(acc[a][t][1] + bb[1]);
                v.z = gelu_f(acc[a][t][2] + bb[2]);
                v.w = gelu_f(acc[a][t][3] + bb[3]);
                *(float4*)&Yf[(((size_t)b << 10) + n) * 64 + mbase] = v;
            }
        }
    }
}

// ---------------------------------------------------------------------------
// Fused Q + K + V projections — R5-measured 47 µs form, verbatim:
// grid (4, 12, 16); z<8: Q path batch z; z>=8: KV path batch z-8 (shared
// B-frags). In-loop loads (R6/R7 showed dbuf and thin tiles both regress).
// ---------------------------------------------------------------------------
__global__ __launch_bounds__(256) void k_gemm_qkv(
    const ushort* __restrict__ qwb, const ushort* __restrict__ kwb,
    const ushort* __restrict__ vwb,
    const ushort* __restrict__ qXT, const ushort* __restrict__ smpT,
    const float* __restrict__ q_b, const float* __restrict__ k_b,
    const float* __restrict__ v_b,
    ushort* __restrict__ qTb, ushort* __restrict__ kTb, ushort* __restrict__ vTb)
{
    const int nb = blockIdx.x, mb = blockIdx.y;
    const int w = threadIdx.x >> 6, lane = threadIdx.x & 63;
    const int l16 = lane & 15, quad = lane >> 4;
    const int m0 = mb * 32;
    const int n0 = nb * 256 + w * 64;
    const int K = NCn;
    floatx4 zero = {0.0f, 0.0f, 0.0f, 0.0f};

    if (blockIdx.z < Bn) {
        const int b = blockIdx.z;
        floatx4 acc[2][4] = {{zero, zero, zero, zero}, {zero, zero, zero, zero}};
        const ushort* a0 = qwb + (size_t)(m0 + l16) * K + quad * 8;
        const ushort* a1 = a0 + (size_t)16 * K;
        const ushort* bp = qXT + ((size_t)b * NQn + n0 + l16) * K + quad * 8;

        #pragma unroll 2
        for (int k0 = 0; k0 < K; k0 += 32) {
            short8 af0 = *(const short8*)(a0 + k0);
            short8 af1 = *(const short8*)(a1 + k0);
            short8 bf[4];
            #pragma unroll
            for (int t = 0; t < 4; ++t)
                bf[t] = *(const short8*)(bp + (size_t)(t * 16) * K + k0);
            #pragma unroll
            for (int t = 0; t < 4; ++t) {
                acc[0][t] = __builtin_amdgcn_mfma_f32_16x16x32_bf16(af0, bf[t], acc[0][t], 0, 0, 0);
                acc[1][t] = __builtin_amdgcn_mfma_f32_16x16x32_bf16(af1, bf[t], acc[1][t], 0, 0, 0);
            }
        }
        #pragma unroll
        for (int a = 0; a < 2; ++a)
            #pragma unroll
            for (int r = 0; r < 4; ++r) {
                int m = m0 + a * 16 + quad * 4 + r;
                int head = m >> 5, d = m & 31;
                float bb = q_b[m];
                #pragma unroll
                for (int t2 = 0; t2 < 4; ++t2) {
                    int n = n0 + t2 * 16 + l16;   // always < 1024
                    qTb[((size_t)(b * HEADSn + head) * NQn + n) * 32 + d] =
                        f2bf(acc[a][t2][r] + bb);
                }
            }
    } else {
        const int b = blockIdx.z - Bn;
        floatx4 acck[2][4] = {{zero, zero, zero, zero}, {zero, zero, zero, zero}};
        floatx4 accv[2][4] = {{zero, zero, zero, zero}, {zero, zero, zero, zero}};
        const ushort* ak0 = kwb + (size_t)(m0 + l16) * K + quad * 8;
        const ushort* av0 = vwb + (size_t)(m0 + l16) * K + quad * 8;
        const ushort* bp  = smpT + ((size_t)b * NQn + n0 + l16) * K + quad * 8;

        for (int k0 = 0; k0 < K; k0 += 32) {
            short8 afk0 = *(const short8*)(ak0 + k0);
            short8 afk1 = *(const short8*)(ak0 + (size_t)16 * K + k0);
            short8 afv0 = *(const short8*)(av0 + k0);
            short8 afv1 = *(const short8*)(av0 + (size_t)16 * K + k0);
            short8 bf[4];
            #pragma unroll
            for (int t = 0; t < 4; ++t)
                bf[t] = *(const short8*)(bp + (size_t)(t * 16) * K + k0);
            #pragma unroll
            for (int t = 0; t < 4; ++t) {
                acck[0][t] = __builtin_amdgcn_mfma_f32_16x16x32_bf16(afk0, bf[t], acck[0][t], 0, 0, 0);
                acck[1][t] = __builtin_amdgcn_mfma_f32_16x16x32_bf16(afk1, bf[t], acck[1][t], 0, 0, 0);
                accv[0][t] = __builtin_amdgcn_mfma_f32_16x16x32_bf16(afv0, bf[t], accv[0][t], 0, 0, 0);
                accv[1][t] = __builtin_amdgcn_mfma_f32_16x16x32_bf16(afv1, bf[t], accv[1][t], 0, 0, 0);
            }
        }
        #pragma unroll
        for (int a = 0; a < 2; ++a)
            #pragma unroll
            for (int r = 0; r < 4; ++r) {
                int m = m0 + a * 16 + quad * 4 + r;
                int head = m >> 5, d = m & 31;
                float bk = k_b[m], bv = v_b[m];
                #pragma unroll
                for (int t2 = 0; t2 < 4; ++t2) {
                    int n = n0 + t2 * 16 + l16;
                    if (n < NKVn)
                        kTb[((size_t)(b * HEADSn + head) * NKVn + n) * 32 + d] =
                            f2bf(acck[a][t2][r] + bk);
                    if (n < VSTRIDE)
                        vTb[((size_t)b * NCn + m) * VSTRIDE + n] =
                            (n < NKVn) ? f2bf(accv[a][t2][r] + bv) : (ushort)0;
                }
            }
    }
}

// ---------------------------------------------------------------------------
// Flash attention, bf16 MFMA, 32 queries/wave, K/V register prefetch.
// 768 blocks 1-D: b = id%8, j = id/8: h = j%12, mt = j/12.
// ---------------------------------------------------------------------------
__global__ __launch_bounds__(256) void k_attn_mfma(
    const ushort* __restrict__ qT, const ushort* __restrict__ kT,
    const ushort* __restrict__ vb, ushort* __restrict__ aoutT)
{
    __shared__ __align__(16) ushort p_lds[4 * 2 * 16 * 80];   // 20.5 KB
    const int b = blockIdx.x & 7;
    const int j = blockIdx.x >> 3;          // 0..95
    const int h = j % HEADSn, mt = j / HEADSn;   // mt 0..7
    const int bh = b * HEADSn + h;
    const int tid = threadIdx.x;
    const int w = tid >> 6, lane = tid & 63;
    const int l16 = lane & 15, quad = lane >> 4;
    const float cexp = 0.25503486f;   // (1/sqrt(32)) * log2(e)

    ushort* p_w[2] = { p_lds + (w * 2 + 0) * (16 * 80),
                       p_lds + (w * 2 + 1) * (16 * 80) };

    const int q0 = mt * 128 + w * 32;
    short8 qf[2];
    qf[0] = *(const short8*)(qT + (size_t)((bh * NQn + q0 + l16) * 32 + quad * 8));
    qf[1] = *(const short8*)(qT + (size_t)((bh * NQn + q0 + 16 + l16) * 32 + quad * 8));

    const ushort* kbase = kT + (size_t)bh * NKVn * 32;
    const ushort* vbase = vb + ((size_t)b * NCn + h * Dn) * VSTRIDE;

    floatx4 zero = {0.0f, 0.0f, 0.0f, 0.0f};
    floatx4 oacc[2][2] = {{zero, zero}, {zero, zero}};
    float lrun[2][4] = {};

    short8 kf[4];
    #pragma unroll
    for (int t = 0; t < 4; ++t)
        kf[t] = *(const short8*)(kbase + (size_t)((t * 16 + l16) * 32 + quad * 8));

    for (int nc = 0; nc < 15; ++nc) {
        const int n0 = nc * 64;
        short8 vf[2][2];
        #pragma unroll
        for (int kc = 0; kc < 2; ++kc)
            #pragma unroll
            for (int nt2 = 0; nt2 < 2; ++nt2)
                vf[kc][nt2] = *(const short8*)(vbase +
                    (size_t)((nt2 * 16 + l16) * VSTRIDE + n0 + kc * 32 + quad * 8));

        floatx4 sf[2][4];
        #pragma unroll
        for (int a = 0; a < 2; ++a)
            #pragma unroll
            for (int t = 0; t < 4; ++t)
                sf[a][t] = __builtin_amdgcn_mfma_f32_16x16x32_bf16(qf[a], kf[t], zero, 0, 0, 0);

        if (nc < 14) {
            #pragma unroll
            for (int t = 0; t < 4; ++t)
                kf[t] = *(const short8*)(kbase +
                    (size_t)((n0 + 64 + t * 16 + l16) * 32 + quad * 8));
        }

        if (n0 + 64 <= NKVn) {
            #pragma unroll
            for (int a = 0; a < 2; ++a)
                #pragma unroll
                for (int t = 0; t < 4; ++t)
                    #pragma unroll
                    for (int r = 0; r < 4; ++r) {
                        float p = exp2f(sf[a][t][r] * cexp);
                        lrun[a][r] += p;
                        p_w[a][(quad * 4 + r) * 80 + t * 16 + l16] = f2bf_fast(p);
                    }
        } else {
            const int limit = NKVn - n0;
            #pragma unroll
            for (int a = 0; a < 2; ++a)
                #pragma unroll
                for (int t = 0; t < 4; ++t) {
                    const int col = t * 16 + l16;
                    #pragma unroll
                    for (int r = 0; r < 4; ++r) {
                        float p = (col < limit) ? exp2f(sf[a][t][r] * cexp) : 0.0f;
                        lrun[a][r] += p;
                        p_w[a][(quad * 4 + r) * 80 + col] = f2bf_fast(p);
                    }
                }
        }

        #pragma unroll
        for (int a = 0; a < 2; ++a)
            #pragma unroll
            for (int kc = 0; kc < 2; ++kc) {
                const short8 pf = *(const short8*)(p_w[a] + l16 * 80 + kc * 32 + quad * 8);
                #pragma unroll
                for (int nt2 = 0; nt2 < 2; ++nt2)
                    oacc[a][nt2] = __builtin_amdgcn_mfma_f32_16x16x32_bf16(
                        pf, vf[kc][nt2], oacc[a][nt2], 0, 0, 0);
            }
    }

    #pragma unroll
    for (int a = 0; a < 2; ++a)
        #pragma unroll
        for (int r = 0; r < 4; ++r) {
            float l = lrun[a][r];
            l += __shfl_xor(l, 1, 64);
            l += __shfl_xor(l, 2, 64);
            l += __shfl_xor(l, 4, 64);
            l += __shfl_xor(l, 8, 64);
            lrun[a][r] = 1.0f / l;
        }

    #pragma unroll
    for (int a = 0; a < 2; ++a)
        #pragma unroll
        for (int nt2 = 0; nt2 < 2; ++nt2)
            #pragma unroll
            for (int r = 0; r < 4; ++r) {
                int m = q0 + a * 16 + quad * 4 + r;
                int d = h * Dn + nt2 * 16 + l16;
                aoutT[((size_t)b * NQn + m) * NCn + d] =
                    f2bf(oacc[a][nt2][r] * lrun[a][r]);
            }
}

// ---------------------------------------------------------------------------
extern "C" void kernel_launch(void* const* d_in, const int* in_sizes, int n_in,
                              void* d_out, int out_size, void* d_ws, size_t ws_size,
                              hipStream_t stream) {
    const float* query = (const float*)d_in[0];
    const float* xr1   = (const float*)d_in[1];
    const float* xr2   = (const float*)d_in[2];
    const float* xx1   = (const float*)d_in[3];
    const float* xx2   = (const float*)d_in[4];
    const float* w1    = (const float*)d_in[5];
    const float* b1    = (const float*)d_in[6];
    const float* w2    = (const float*)d_in[7];
    const float* b2    = (const float*)d_in[8];
    const float* w3    = (const float*)d_in[9];
    const float* q_w   = (const float*)d_in[10];
    const float* q_b   = (const float*)d_in[11];
    const float* k_w   = (const float*)d_in[12];
    const float* k_b   = (const float*)d_in[13];
    const float* v_w   = (const float*)d_in[14];
    const float* v_b   = (const float*)d_in[15];
    const float* o_w   = (const float*)d_in[16];
    const float* o_b   = (const float*)d_in[17];
    float* out = (float*)d_out;

    // ---- workspace layout (float units), with liveness overlap ----
    float* ws = (float*)d_ws;
    ushort* dataT = (ushort*)ws;                   // 48*1024*256 u = 6,291,456 f
    ushort* qTb   = (ushort*)(ws + 1572864);       // 8*12*1024*32 u (after dataT dead? no —
                                                   //  qTb written by qkv, dataT dead then ✓)
    ushort* aoutT = (ushort*)(ws + 3145728);       // 8*1024*384 u
    float*  t1T   = ws + 6291456;                  // 48*1024*64 fp32 = 3,145,728 f
    ushort* kTb   = (ushort*)(ws + 6291456);       // overlays t1T after offsample ✓
    ushort* vTb   = (ushort*)(ws + 7673856);       // 8*384*960 u; pads zero-written
    ushort* smpT  = (ushort*)(ws + 9458816);       // 8*1024*384 u = 1,572,864 f
    ushort* wb    = (ushort*)(ws + 11031680);      // 606,208 u
    ushort* w1b = wb;
    ushort* qwb = wb + 16384;
    ushort* kwb = wb + 163840;
    ushort* vwb = wb + 311296;
    ushort* owb = wb + 458752;
    ushort* qXT2 = wb + 606208;                    // 8*1024*384 u (own slot: k_prep
                                                   //  writes it concurrently with dataT)

    k_prep<<<dim3(1024), 256, 0, stream>>>(xr1, xr2, xx1, xx2, query,
                                           w1, q_w, k_w, v_w, o_w,
                                           dataT, qXT2, wb);
    k_gemm<<<dim3(4, 2, 48), 256, 0, stream>>>(w1b, dataT, b1, nullptr,
                                               t1T, 256, NQn, NQn, 3);
    k_offsample<<<dim3(48, 4), 256, 0, stream>>>(t1T, w2, b2, w3,
                                                 xr1, xr2, xx1, xx2, smpT);
    k_gemm_qkv<<<dim3(4, 12, 16), 256, 0, stream>>>(qwb, kwb, vwb, qXT2, smpT,
                                                    q_b, k_b, v_b, qTb, kTb, vTb);
    k_attn_mfma<<<dim3(768), 256, 0, stream>>>(qTb, kTb, vTb, aoutT);
    k_gemm<<<dim3(4, 12, Bn), 256, 0, stream>>>(owb, aoutT, o_b, query,
                                                out, NCn, NQn, NQn, 0);
}

// Round 10
// 297.628 us; speedup vs baseline: 1.1492x; 1.1492x over previous
//
#include <hip/hip_runtime.h>
#include <math.h>

#define Bn 8
#define NCn 384
#define Hn 32
#define Wn 32
#define Gn 6
#define GCn 64
#define HEADSn 12
#define Dn 32
#define HKn 15
#define WKn 15
#define NSn 225
#define NQn 1024
#define NKVn 900
#define VSTRIDE 960   // V row stride in bf16; covers max frag read (offset 960);
                      // keys 900..959 zero-filled (stale-bits NaN guard, R3 bug).

typedef __attribute__((ext_vector_type(8))) short short8;
typedef __attribute__((ext_vector_type(4))) float floatx4;

__device__ __forceinline__ float gelu_f(float x) {
    return 0.5f * x * (1.0f + erff(x * 0.70710678118654752f));
}

__device__ __forceinline__ ushort f2bf(float x) {
    unsigned u = __float_as_uint(x);
    u = (u + 0x7FFF + ((u >> 16) & 1)) >> 16;   // RNE
    return (ushort)u;
}

// cheap round-half-up bf16 pack (hot P path; <= 1 ulp vs RNE)
__device__ __forceinline__ ushort f2bf_fast(float x) {
    return (ushort)((__float_as_uint(x) + 0x8000u) >> 16);
}

// ---------------------------------------------------------------------------
// k_prep: fused preprocessing, one launch, 1024 blocks.
//  id [0,768):    transpose4 -> dataT (48,1024,256) bf16   (bg=id%48, hwt=id/48)
//  id [768,896):  transposeQ -> qXT  (8,1024,384) bf16     (b=j&7, hwt=j>>3)
//  id [896,1024): cvtw grid-stride -> wb (606208 bf16)
// ---------------------------------------------------------------------------
__global__ __launch_bounds__(256) void k_prep(
    const float* __restrict__ xr1, const float* __restrict__ xr2,
    const float* __restrict__ xx1, const float* __restrict__ xx2,
    const float* __restrict__ query,
    const float* __restrict__ w1, const float* __restrict__ qw,
    const float* __restrict__ kw, const float* __restrict__ vw,
    const float* __restrict__ ow,
    ushort* __restrict__ dataT, ushort* __restrict__ qXT,
    ushort* __restrict__ wb)
{
    __shared__ float lds[64 * 65];
    const int id = blockIdx.x;
    const int tid = threadIdx.x;

    if (id < 768) {
        const int bg = id % 48, hwt = id / 48;
        const int b = bg / Gn, g = bg % Gn;
        for (int kc = 0; kc < 4; ++kc) {
            for (int idx = tid; idx < 4096; idx += 256) {
                int cl = idx >> 6, hwl = idx & 63;
                int gch = g * 256 + kc * 64 + cl;
                int m = gch / NCn, cm = gch % NCn;
                const float* img = (m == 0) ? xr1 : (m == 1) ? xr2 : (m == 2) ? xx1 : xx2;
                lds[cl * 65 + hwl] = img[(b * NCn + cm) * NQn + hwt * 64 + hwl];
            }
            __syncthreads();
            for (int idx = tid; idx < 4096; idx += 256) {
                int hwl = idx >> 6, cl = idx & 63;
                dataT[((size_t)bg * NQn + hwt * 64 + hwl) * 256 + kc * 64 + cl] =
                    f2bf(lds[cl * 65 + hwl]);
            }
            __syncthreads();
        }
    } else if (id < 896) {
        const int j = id - 768;
        const int b = j & 7, hwt = j >> 3;
        for (int kc = 0; kc < 6; ++kc) {
            for (int idx = tid; idx < 4096; idx += 256) {
                int cl = idx >> 6, hwl = idx & 63;
                lds[cl * 65 + hwl] =
                    query[((size_t)b * NCn + kc * 64 + cl) * NQn + hwt * 64 + hwl];
            }
            __syncthreads();
            for (int idx = tid; idx < 4096; idx += 256) {
                int hwl = idx >> 6, cl = idx & 63;
                qXT[((size_t)b * NQn + hwt * 64 + hwl) * NCn + kc * 64 + cl] =
                    f2bf(lds[cl * 65 + hwl]);
            }
            __syncthreads();
        }
    } else {
        const int j = id - 896;   // 0..127
        for (int i = j * 256 + tid; i < 606208; i += 128 * 256) {
            float v;
            if      (i < 16384)  v = w1[i];
            else if (i < 163840) v = qw[i - 16384];
            else if (i < 311296) v = kw[i - 163840];
            else if (i < 458752) v = vw[i - 311296];
            else                 v = ow[i - 458752];
            wb[i] = f2bf(v);
        }
    }
}

// ---------------------------------------------------------------------------
// k_offsets: depthwise 3x3 stride2 + GELU + 1x1 (64->2) + tanh -> pixel coords.
// Wave-per-sample: needs 10800 waves -> grid 2700 blocks x 4 waves.
// (R9 bug: launched 675 blocks = 2700 waves, leaving 75% of posb stale.)
// t1T is (bg, hw, c) fp32: each tap is a 256B lane-contiguous read.
// ---------------------------------------------------------------------------
__global__ __launch_bounds__(256) void k_offsets(
    const float* __restrict__ t1T, const float* __restrict__ w2,
    const float* __restrict__ b2, const float* __restrict__ w3,
    float* __restrict__ posb)
{
    const int wid  = blockIdx.x * 4 + (threadIdx.x >> 6);   // 0..10799
    const int lane = threadIdx.x & 63;
    const int bg = wid / NSn, s = wid % NSn;
    const int hk = s / WKn, wk = s % WKn;

    const float* tbase = t1T + ((size_t)bg << 10) * 64;
    const float* wp = w2 + lane * 9;
    float sv = b2[lane];
    #pragma unroll
    for (int i = 0; i < 3; ++i)
        #pragma unroll
        for (int j = 0; j < 3; ++j)
            sv += tbase[(size_t)(((hk * 2 + i) * Wn + wk * 2 + j) * 64 + lane)] * wp[i * 3 + j];
    float gv = gelu_f(sv);
    float ay = w3[lane] * gv;
    float ax = w3[64 + lane] * gv;
    #pragma unroll
    for (int off = 32; off > 0; off >>= 1) {
        ay += __shfl_xor(ay, off, 64);
        ax += __shfl_xor(ax, off, 64);
    }
    if (lane == 0) {
        float fy = tanhf(ay) * (2.0f / 14.0f);
        float fx = tanhf(ax) * (2.0f / 14.0f);
        float cy = (float)(hk * 2 + 1) * (2.0f / 31.0f) - 1.0f;
        float cx = (float)(wk * 2 + 1) * (2.0f / 31.0f) - 1.0f;
        float py = fminf(fmaxf(fy + cy, -1.0f), 1.0f);
        float px = fminf(fmaxf(fx + cx, -1.0f), 1.0f);
        posb[wid * 2 + 0] = (py + 1.0f) * 0.5f * 31.0f;
        posb[wid * 2 + 1] = (px + 1.0f) * 0.5f * 31.0f;
    }
}

// ---------------------------------------------------------------------------
// k_sample: bilinear gathers -> smpT (8, 1024(pad), 384) bf16, c-inner writes.
// Grid (192, 4): x = (b,g,m) flat, y = 57-sample chunk -> 768 blocks for TLP.
// ---------------------------------------------------------------------------
__global__ __launch_bounds__(256) void k_sample(
    const float* __restrict__ xr1, const float* __restrict__ xr2,
    const float* __restrict__ xx1, const float* __restrict__ xx2,
    const float* __restrict__ posb, ushort* __restrict__ smpT)
{
    const int b = blockIdx.x & 7;
    const int j = blockIdx.x >> 3;          // 0..23
    const int g = j % Gn, m = j / Gn;       // m 0..3
    const int bg = b * Gn + g;
    const int s0 = blockIdx.y * 57;
    const int ns = min(57, NSn - s0);       // 57,57,57,54
    const float* img = (m == 0) ? xr1 : (m == 1) ? xr2 : (m == 2) ? xx1 : xx2;

    for (int idx = threadIdx.x; idx < 64 * ns; idx += 256) {
        int c = idx & 63, s = s0 + (idx >> 6);
        float py = posb[(bg * NSn + s) * 2 + 0];
        float px = posb[(bg * NSn + s) * 2 + 1];
        float y0f = floorf(py), x0f = floorf(px);
        float wy = py - y0f, wx = px - x0f;
        int y0 = (int)y0f, x0 = (int)x0f;
        int y1 = min(y0 + 1, Hn - 1), x1 = min(x0 + 1, Wn - 1);
        const float* base = img + (b * NCn + g * GCn + c) * NQn;
        float v00 = base[y0 * Wn + x0], v01 = base[y0 * Wn + x1];
        float v10 = base[y1 * Wn + x0], v11 = base[y1 * Wn + x1];
        float v = v00 * (1.0f - wy) * (1.0f - wx) + v01 * (1.0f - wy) * wx
                + v10 * wy * (1.0f - wx) + v11 * wy * wx;
        smpT[((size_t)b * NQn + m * NSn + s) * NCn + g * GCn + c] = f2bf(v);
    }
}

// ---------------------------------------------------------------------------
// MFMA GEMM (R5-measured form: simple in-loop loads, compiler-scheduled).
// C[b,m,n] = sum_k A[m,k] * XT[b,n,k]; grid (nb, mb, b); wave tile 32m x 64n.
// mode 0: fp32 (b,384,N) + resid
// mode 3: GELU -> t1T (bg, hw, c) fp32, float4 over the m-contiguous r regs
// ---------------------------------------------------------------------------
__global__ __launch_bounds__(256) void k_gemm(
    const ushort* __restrict__ A, const ushort* __restrict__ XT,
    const float* __restrict__ bias, const float* __restrict__ resid,
    float* __restrict__ Yf,
    int K, int Npad, int N, int mode)
{
    const int nb = blockIdx.x, mb = blockIdx.y, b = blockIdx.z;
    const int w = threadIdx.x >> 6, lane = threadIdx.x & 63;
    const int l16 = lane & 15, quad = lane >> 4;
    const int m0 = mb * 32;
    const int n0 = nb * 256 + w * 64;

    floatx4 zero = {0.0f, 0.0f, 0.0f, 0.0f};
    floatx4 acc[2][4] = {{zero, zero, zero, zero}, {zero, zero, zero, zero}};

    const ushort* a0 = A + (size_t)(m0 + l16) * K + quad * 8;
    const ushort* a1 = a0 + (size_t)16 * K;
    const ushort* bp = XT + ((size_t)b * Npad + n0 + l16) * K + quad * 8;

    #pragma unroll 2
    for (int k0 = 0; k0 < K; k0 += 32) {
        short8 af0 = *(const short8*)(a0 + k0);
        short8 af1 = *(const short8*)(a1 + k0);
        short8 bf[4];
        #pragma unroll
        for (int t = 0; t < 4; ++t)
            bf[t] = *(const short8*)(bp + (size_t)(t * 16) * K + k0);
        #pragma unroll
        for (int t = 0; t < 4; ++t) {
            acc[0][t] = __builtin_amdgcn_mfma_f32_16x16x32_bf16(af0, bf[t], acc[0][t], 0, 0, 0);
            acc[1][t] = __builtin_amdgcn_mfma_f32_16x16x32_bf16(af1, bf[t], acc[1][t], 0, 0, 0);
        }
    }

    if (mode == 0) {
        #pragma unroll
        for (int a = 0; a < 2; ++a)
            #pragma unroll
            for (int r = 0; r < 4; ++r) {
                int m = m0 + a * 16 + quad * 4 + r;
                float bb = bias[m];
                #pragma unroll
                for (int t = 0; t < 4; ++t) {
                    int n = n0 + t * 16 + l16;
                    size_t o = ((size_t)b * NCn + m) * N + n;
                    Yf[o] = acc[a][t][r] + bb + resid[o];
                }
            }
    } else {  // mode 3: GELU -> t1T (bg, hw, c): float4 over r (m-contiguous)
        #pragma unroll
        for (int a = 0; a < 2; ++a) {
            const int mbase = m0 + a * 16 + quad * 4;     // 4-aligned
            float bb[4];
            #pragma unroll
            for (int r = 0; r < 4; ++r) bb[r] = bias[mbase + r];
            #pragma unroll
            for (int t = 0; t < 4; ++t) {
                int n = n0 + t * 16 + l16;
                float4 v;
                v.x = gelu_f(acc[a][t][0] + bb[0]);
                v.y = gelu_f(acc[a][t][1] + bb[1]);
                v.z = gelu_f(acc[a][t][2] + bb[2]);
                v.w = gelu_f(acc[a][t][3] + bb[3]);
                *(float4*)&Yf[(((size_t)b << 10) + n) * 64 + mbase] = v;
            }
        }
    }
}

// ---------------------------------------------------------------------------
// Fused Q + K + V projections — R5-measured 47 µs form, verbatim:
// grid (4, 12, 16); z<8: Q path batch z; z>=8: KV path batch z-8 (shared
// B-frags). In-loop loads (R6/R7 showed dbuf and thin tiles both regress).
// ---------------------------------------------------------------------------
__global__ __launch_bounds__(256) void k_gemm_qkv(
    const ushort* __restrict__ qwb, const ushort* __restrict__ kwb,
    const ushort* __restrict__ vwb,
    const ushort* __restrict__ qXT, const ushort* __restrict__ smpT,
    const float* __restrict__ q_b, const float* __restrict__ k_b,
    const float* __restrict__ v_b,
    ushort* __restrict__ qTb, ushort* __restrict__ kTb, ushort* __restrict__ vTb)
{
    const int nb = blockIdx.x, mb = blockIdx.y;
    const int w = threadIdx.x >> 6, lane = threadIdx.x & 63;
    const int l16 = lane & 15, quad = lane >> 4;
    const int m0 = mb * 32;
    const int n0 = nb * 256 + w * 64;
    const int K = NCn;
    floatx4 zero = {0.0f, 0.0f, 0.0f, 0.0f};

    if (blockIdx.z < Bn) {
        const int b = blockIdx.z;
        floatx4 acc[2][4] = {{zero, zero, zero, zero}, {zero, zero, zero, zero}};
        const ushort* a0 = qwb + (size_t)(m0 + l16) * K + quad * 8;
        const ushort* a1 = a0 + (size_t)16 * K;
        const ushort* bp = qXT + ((size_t)b * NQn + n0 + l16) * K + quad * 8;

        #pragma unroll 2
        for (int k0 = 0; k0 < K; k0 += 32) {
            short8 af0 = *(const short8*)(a0 + k0);
            short8 af1 = *(const short8*)(a1 + k0);
            short8 bf[4];
            #pragma unroll
            for (int t = 0; t < 4; ++t)
                bf[t] = *(const short8*)(bp + (size_t)(t * 16) * K + k0);
            #pragma unroll
            for (int t = 0; t < 4; ++t) {
                acc[0][t] = __builtin_amdgcn_mfma_f32_16x16x32_bf16(af0, bf[t], acc[0][t], 0, 0, 0);
                acc[1][t] = __builtin_amdgcn_mfma_f32_16x16x32_bf16(af1, bf[t], acc[1][t], 0, 0, 0);
            }
        }
        #pragma unroll
        for (int a = 0; a < 2; ++a)
            #pragma unroll
            for (int r = 0; r < 4; ++r) {
                int m = m0 + a * 16 + quad * 4 + r;
                int head = m >> 5, d = m & 31;
                float bb = q_b[m];
                #pragma unroll
                for (int t2 = 0; t2 < 4; ++t2) {
                    int n = n0 + t2 * 16 + l16;   // always < 1024
                    qTb[((size_t)(b * HEADSn + head) * NQn + n) * 32 + d] =
                        f2bf(acc[a][t2][r] + bb);
                }
            }
    } else {
        const int b = blockIdx.z - Bn;
        floatx4 acck[2][4] = {{zero, zero, zero, zero}, {zero, zero, zero, zero}};
        floatx4 accv[2][4] = {{zero, zero, zero, zero}, {zero, zero, zero, zero}};
        const ushort* ak0 = kwb + (size_t)(m0 + l16) * K + quad * 8;
        const ushort* av0 = vwb + (size_t)(m0 + l16) * K + quad * 8;
        const ushort* bp  = smpT + ((size_t)b * NQn + n0 + l16) * K + quad * 8;

        for (int k0 = 0; k0 < K; k0 += 32) {
            short8 afk0 = *(const short8*)(ak0 + k0);
            short8 afk1 = *(const short8*)(ak0 + (size_t)16 * K + k0);
            short8 afv0 = *(const short8*)(av0 + k0);
            short8 afv1 = *(const short8*)(av0 + (size_t)16 * K + k0);
            short8 bf[4];
            #pragma unroll
            for (int t = 0; t < 4; ++t)
                bf[t] = *(const short8*)(bp + (size_t)(t * 16) * K + k0);
            #pragma unroll
            for (int t = 0; t < 4; ++t) {
                acck[0][t] = __builtin_amdgcn_mfma_f32_16x16x32_bf16(afk0, bf[t], acck[0][t], 0, 0, 0);
                acck[1][t] = __builtin_amdgcn_mfma_f32_16x16x32_bf16(afk1, bf[t], acck[1][t], 0, 0, 0);
                accv[0][t] = __builtin_amdgcn_mfma_f32_16x16x32_bf16(afv0, bf[t], accv[0][t], 0, 0, 0);
                accv[1][t] = __builtin_amdgcn_mfma_f32_16x16x32_bf16(afv1, bf[t], accv[1][t], 0, 0, 0);
            }
        }
        #pragma unroll
        for (int a = 0; a < 2; ++a)
            #pragma unroll
            for (int r = 0; r < 4; ++r) {
                int m = m0 + a * 16 + quad * 4 + r;
                int head = m >> 5, d = m & 31;
                float bk = k_b[m], bv = v_b[m];
                #pragma unroll
                for (int t2 = 0; t2 < 4; ++t2) {
                    int n = n0 + t2 * 16 + l16;
                    if (n < NKVn)
                        kTb[((size_t)(b * HEADSn + head) * NKVn + n) * 32 + d] =
                            f2bf(acck[a][t2][r] + bk);
                    if (n < VSTRIDE)
                        vTb[((size_t)b * NCn + m) * VSTRIDE + n] =
                            (n < NKVn) ? f2bf(accv[a][t2][r] + bv) : (ushort)0;
                }
            }
    }
}

// ---------------------------------------------------------------------------
// Flash attention, bf16 MFMA, 32 queries/wave, K/V register prefetch.
// 768 blocks 1-D: b = id%8, j = id/8: h = j%12, mt = j/12.
// ---------------------------------------------------------------------------
__global__ __launch_bounds__(256) void k_attn_mfma(
    const ushort* __restrict__ qT, const ushort* __restrict__ kT,
    const ushort* __restrict__ vb, ushort* __restrict__ aoutT)
{
    __shared__ __align__(16) ushort p_lds[4 * 2 * 16 * 80];   // 20.5 KB
    const int b = blockIdx.x & 7;
    const int j = blockIdx.x >> 3;          // 0..95
    const int h = j % HEADSn, mt = j / HEADSn;   // mt 0..7
    const int bh = b * HEADSn + h;
    const int tid = threadIdx.x;
    const int w = tid >> 6, lane = tid & 63;
    const int l16 = lane & 15, quad = lane >> 4;
    const float cexp = 0.25503486f;   // (1/sqrt(32)) * log2(e)

    ushort* p_w[2] = { p_lds + (w * 2 + 0) * (16 * 80),
                       p_lds + (w * 2 + 1) * (16 * 80) };

    const int q0 = mt * 128 + w * 32;
    short8 qf[2];
    qf[0] = *(const short8*)(qT + (size_t)((bh * NQn + q0 + l16) * 32 + quad * 8));
    qf[1] = *(const short8*)(qT + (size_t)((bh * NQn + q0 + 16 + l16) * 32 + quad * 8));

    const ushort* kbase = kT + (size_t)bh * NKVn * 32;
    const ushort* vbase = vb + ((size_t)b * NCn + h * Dn) * VSTRIDE;

    floatx4 zero = {0.0f, 0.0f, 0.0f, 0.0f};
    floatx4 oacc[2][2] = {{zero, zero}, {zero, zero}};
    float lrun[2][4] = {};

    short8 kf[4];
    #pragma unroll
    for (int t = 0; t < 4; ++t)
        kf[t] = *(const short8*)(kbase + (size_t)((t * 16 + l16) * 32 + quad * 8));

    for (int nc = 0; nc < 15; ++nc) {
        const int n0 = nc * 64;
        short8 vf[2][2];
        #pragma unroll
        for (int kc = 0; kc < 2; ++kc)
            #pragma unroll
            for (int nt2 = 0; nt2 < 2; ++nt2)
                vf[kc][nt2] = *(const short8*)(vbase +
                    (size_t)((nt2 * 16 + l16) * VSTRIDE + n0 + kc * 32 + quad * 8));

        floatx4 sf[2][4];
        #pragma unroll
        for (int a = 0; a < 2; ++a)
            #pragma unroll
            for (int t = 0; t < 4; ++t)
                sf[a][t] = __builtin_amdgcn_mfma_f32_16x16x32_bf16(qf[a], kf[t], zero, 0, 0, 0);

        if (nc < 14) {
            #pragma unroll
            for (int t = 0; t < 4; ++t)
                kf[t] = *(const short8*)(kbase +
                    (size_t)((n0 + 64 + t * 16 + l16) * 32 + quad * 8));
        }

        if (n0 + 64 <= NKVn) {
            #pragma unroll
            for (int a = 0; a < 2; ++a)
                #pragma unroll
                for (int t = 0; t < 4; ++t)
                    #pragma unroll
                    for (int r = 0; r < 4; ++r) {
                        float p = exp2f(sf[a][t][r] * cexp);
                        lrun[a][r] += p;
                        p_w[a][(quad * 4 + r) * 80 + t * 16 + l16] = f2bf_fast(p);
                    }
        } else {
            const int limit = NKVn - n0;
            #pragma unroll
            for (int a = 0; a < 2; ++a)
                #pragma unroll
                for (int t = 0; t < 4; ++t) {
                    const int col = t * 16 + l16;
                    #pragma unroll
                    for (int r = 0; r < 4; ++r) {
                        float p = (col < limit) ? exp2f(sf[a][t][r] * cexp) : 0.0f;
                        lrun[a][r] += p;
                        p_w[a][(quad * 4 + r) * 80 + col] = f2bf_fast(p);
                    }
                }
        }

        #pragma unroll
        for (int a = 0; a < 2; ++a)
            #pragma unroll
            for (int kc = 0; kc < 2; ++kc) {
                const short8 pf = *(const short8*)(p_w[a] + l16 * 80 + kc * 32 + quad * 8);
                #pragma unroll
                for (int nt2 = 0; nt2 < 2; ++nt2)
                    oacc[a][nt2] = __builtin_amdgcn_mfma_f32_16x16x32_bf16(
                        pf, vf[kc][nt2], oacc[a][nt2], 0, 0, 0);
            }
    }

    #pragma unroll
    for (int a = 0; a < 2; ++a)
        #pragma unroll
        for (int r = 0; r < 4; ++r) {
            float l = lrun[a][r];
            l += __shfl_xor(l, 1, 64);
            l += __shfl_xor(l, 2, 64);
            l += __shfl_xor(l, 4, 64);
            l += __shfl_xor(l, 8, 64);
            lrun[a][r] = 1.0f / l;
        }

    #pragma unroll
    for (int a = 0; a < 2; ++a)
        #pragma unroll
        for (int nt2 = 0; nt2 < 2; ++nt2)
            #pragma unroll
            for (int r = 0; r < 4; ++r) {
                int m = q0 + a * 16 + quad * 4 + r;
                int d = h * Dn + nt2 * 16 + l16;
                aoutT[((size_t)b * NQn + m) * NCn + d] =
                    f2bf(oacc[a][nt2][r] * lrun[a][r]);
            }
}

// ---------------------------------------------------------------------------
extern "C" void kernel_launch(void* const* d_in, const int* in_sizes, int n_in,
                              void* d_out, int out_size, void* d_ws, size_t ws_size,
                              hipStream_t stream) {
    const float* query = (const float*)d_in[0];
    const float* xr1   = (const float*)d_in[1];
    const float* xr2   = (const float*)d_in[2];
    const float* xx1   = (const float*)d_in[3];
    const float* xx2   = (const float*)d_in[4];
    const float* w1    = (const float*)d_in[5];
    const float* b1    = (const float*)d_in[6];
    const float* w2    = (const float*)d_in[7];
    const float* b2    = (const float*)d_in[8];
    const float* w3    = (const float*)d_in[9];
    const float* q_w   = (const float*)d_in[10];
    const float* q_b   = (const float*)d_in[11];
    const float* k_w   = (const float*)d_in[12];
    const float* k_b   = (const float*)d_in[13];
    const float* v_w   = (const float*)d_in[14];
    const float* v_b   = (const float*)d_in[15];
    const float* o_w   = (const float*)d_in[16];
    const float* o_b   = (const float*)d_in[17];
    float* out = (float*)d_out;

    // ---- workspace layout (float units), with liveness overlap ----
    float* ws = (float*)d_ws;
    ushort* dataT = (ushort*)ws;                   // 48*1024*256 u = 6,291,456 f
    ushort* qTb   = (ushort*)(ws + 1572864);       // 8*12*1024*32 u (dataT dead by qkv) ✓
    ushort* aoutT = (ushort*)(ws + 3145728);       // 8*1024*384 u
    float*  t1T   = ws + 6291456;                  // 48*1024*64 fp32 = 3,145,728 f
    ushort* kTb   = (ushort*)(ws + 6291456);       // overlays t1T (dead after k_offsets) ✓
    ushort* vTb   = (ushort*)(ws + 7673856);       // 8*384*960 u; pads zero-written
    float*  posb  = ws + 9437184;                  // 21,600 f (gap before smpT)
    ushort* smpT  = (ushort*)(ws + 9458816);       // 8*1024*384 u = 1,572,864 f
    ushort* wb    = (ushort*)(ws + 11031680);      // 606,208 u
    ushort* w1b = wb;
    ushort* qwb = wb + 16384;
    ushort* kwb = wb + 163840;
    ushort* vwb = wb + 311296;
    ushort* owb = wb + 458752;
    ushort* qXT2 = wb + 606208;                    // 8*1024*384 u (own slot: k_prep
                                                   //  writes it concurrently with dataT)

    k_prep<<<dim3(1024), 256, 0, stream>>>(xr1, xr2, xx1, xx2, query,
                                           w1, q_w, k_w, v_w, o_w,
                                           dataT, qXT2, wb);
    k_gemm<<<dim3(4, 2, 48), 256, 0, stream>>>(w1b, dataT, b1, nullptr,
                                               t1T, 256, NQn, NQn, 3);
    k_offsets<<<dim3(2700), 256, 0, stream>>>(t1T, w2, b2, w3, posb);
    k_sample<<<dim3(192, 4), 256, 0, stream>>>(xr1, xr2, xx1, xx2, posb, smpT);
    k_gemm_qkv<<<dim3(4, 12, 16), 256, 0, stream>>>(qwb, kwb, vwb, qXT2, smpT,
                                                    q_b, k_b, v_b, qTb, kTb, vTb);
    k_attn_mfma<<<dim3(768), 256, 0, stream>>>(qTb, kTb, vTb, aoutT);
    k_gemm<<<dim3(4, 12, Bn), 256, 0, stream>>>(owb, aoutT, o_b, query,
                                                out, NCn, NQn, NQn, 0);
}